// Round 3
// baseline (1992.188 us; speedup 1.0000x reference)
//
#include <hip/hip_runtime.h>

// TreeLstmDecoder: B=64 trees, K=4, D=6, V=600, L=256, N_PER=1365, N=87360.
// Per-level (tree,pos) state layout -> parent/sibling gathers are identity.
// d<=3: one fused VALU kernel per group (h_pred+logits+softmax+both LSTMs).
// d4/d5: MFMA path with fused kernels; h_pred/logits/gates stay in LDS.

typedef unsigned short u16;
typedef short bf16x8 __attribute__((ext_vector_type(8)));
typedef float f32x4 __attribute__((ext_vector_type(4)));

#define KARY 4
#define NPER 1365

__device__ __forceinline__ float b2f(u16 h) {
  union { unsigned u; float f; } v; v.u = ((unsigned)h) << 16; return v.f;
}
__device__ __forceinline__ u16 f2bf(float f) {
  union { float f; unsigned u; } v; v.f = f;
  unsigned r = v.u + 0x7fff + ((v.u >> 16) & 1);
  return (u16)(r >> 16);
}
__device__ __forceinline__ float sigm(float x) { return 1.f / (1.f + expf(-x)); }

// ---------------- single pack kernel (grid-stride over all packing tasks) ---

__global__ void k_pack(
    const float* __restrict__ z, const float* __restrict__ Wihp,
    const float* __restrict__ Whhp, const float* __restrict__ bihp,
    const float* __restrict__ bhhp, const float* __restrict__ Wihs,
    const float* __restrict__ Whhs, const float* __restrict__ bihs,
    const float* __restrict__ bhhs, const float* __restrict__ Upar,
    const float* __restrict__ Usib, const float* __restrict__ Wlab,
    const float* __restrict__ blab, const float* __restrict__ Wd,
    const float* __restrict__ bd, const float* __restrict__ Ww,
    const float* __restrict__ bw,
    u16* __restrict__ UP, u16* __restrict__ US, u16* __restrict__ WHHP,
    u16* __restrict__ WHHS, u16* __restrict__ ZBF, u16* __restrict__ WIHPT,
    u16* __restrict__ WIHST, u16* __restrict__ WEXT, float* __restrict__ BE,
    float* __restrict__ BP, float* __restrict__ BS) {
  const long T0 = 65536, T1 = 131072, T2 = 393216, T3 = 655360, T4 = 671744,
             T5 = 1286144, T6 = 1900544, T7 = 2054656, T8 = 2055258,
             T9 = 2056282, T10 = 2057306;
  for (long i = (long)blockIdx.x * 256 + threadIdx.x; i < T10;
       i += (long)gridDim.x * 256) {
    if (i < T0) UP[i] = f2bf(Upar[i]);
    else if (i < T1) { long k = i - T0; US[k] = f2bf(Usib[k]); }
    else if (i < T2) { long k = i - T1; WHHP[k] = f2bf(Whhp[k]); }
    else if (i < T3) { long k = i - T2; WHHS[k] = f2bf(Whhs[k]); }
    else if (i < T4) { long k = i - T3; ZBF[k] = f2bf(z[k]); }
    else if (i < T5) { long k = i - T4; int r = (int)(k / 600), c = (int)(k - (long)r * 600);
                       WIHPT[(size_t)c * 1024 + r] = f2bf(Wihp[k]); }
    else if (i < T6) { long k = i - T5; int r = (int)(k / 600), c = (int)(k - (long)r * 600);
                       WIHST[(size_t)c * 1024 + r] = f2bf(Wihs[k]); }
    else if (i < T7) { long k = i - T6; int r = (int)(k >> 8), c = (int)(k & 255);
                       float v = (r < 600) ? Wlab[k] : ((r == 600) ? Wd[c] : Ww[c]);
                       WEXT[k] = f2bf(v); }
    else if (i < T8) { long k = i - T7; BE[k] = (k < 600) ? blab[k] : ((k == 600) ? bd[0] : bw[0]); }
    else if (i < T9) { long k = i - T8; BP[k] = bihp[k] + bhhp[k]; }
    else             { long k = i - T9; BS[k] = bihs[k] + bhhs[k]; }
  }
}

// ---------------- MFMA GEMM (used for PP and GATESP hoists) -----------------

template<int ACT_TANH, int OUT_BF16>
__global__ __launch_bounds__(256) void k_mm(
    const u16* __restrict__ A, const u16* __restrict__ B,
    const float* __restrict__ bias, const u16* __restrict__ Cadd,
    void* __restrict__ Cv, int M, int N) {
  __shared__ __align__(16) u16 As[128 * 40];
  __shared__ __align__(16) u16 Bs[128 * 40];
  const int m0 = blockIdx.x * 128, n0 = blockIdx.y * 128;
  const int tid = threadIdx.x;
  const int wave = tid >> 6, lane = tid & 63;
  const int quad = lane >> 4, lr = lane & 15;
  const int wm = (wave >> 1) * 64, wn = (wave & 1) * 64;
  const int srow = tid >> 2;
  const int sch = (tid & 3) << 3;

  f32x4 acc[4][4] = {};
  for (int t = 0; t < 8; ++t) {
    const int kk = t * 32;
    bf16x8 a0 = *(const bf16x8*)(A + (size_t)(m0 + srow) * 256 + kk + sch);
    bf16x8 a1 = *(const bf16x8*)(A + (size_t)(m0 + srow + 64) * 256 + kk + sch);
    bf16x8 b0 = *(const bf16x8*)(B + (size_t)(n0 + srow) * 256 + kk + sch);
    bf16x8 b1 = *(const bf16x8*)(B + (size_t)(n0 + srow + 64) * 256 + kk + sch);
    __syncthreads();
    *(bf16x8*)&As[srow * 40 + sch] = a0;
    *(bf16x8*)&As[(srow + 64) * 40 + sch] = a1;
    *(bf16x8*)&Bs[srow * 40 + sch] = b0;
    *(bf16x8*)&Bs[(srow + 64) * 40 + sch] = b1;
    __syncthreads();
    bf16x8 af[4], bfr[4];
#pragma unroll
    for (int tm = 0; tm < 4; ++tm)
      af[tm] = *(const bf16x8*)&As[(wm + tm * 16 + lr) * 40 + quad * 8];
#pragma unroll
    for (int tn = 0; tn < 4; ++tn)
      bfr[tn] = *(const bf16x8*)&Bs[(wn + tn * 16 + lr) * 40 + quad * 8];
#pragma unroll
    for (int tm = 0; tm < 4; ++tm)
#pragma unroll
      for (int tn = 0; tn < 4; ++tn)
        acc[tm][tn] = __builtin_amdgcn_mfma_f32_16x16x32_bf16(
            af[tm], bfr[tn], acc[tm][tn], 0, 0, 0);
  }
#pragma unroll
  for (int tn = 0; tn < 4; ++tn) {
    int col = n0 + wn + tn * 16 + lr;
    if (col >= N) continue;
    float bv = bias ? bias[col] : 0.f;
#pragma unroll
    for (int tm = 0; tm < 4; ++tm) {
#pragma unroll
      for (int r = 0; r < 4; ++r) {
        int row = m0 + wm + tm * 16 + quad * 4 + r;
        if (row >= M) continue;
        float v = acc[tm][tn][r] + bv;
        if (Cadd) v += b2f(Cadd[(size_t)row * N + col]);
        if (ACT_TANH) v = tanhf(v);
        if (OUT_BF16) ((u16*)Cv)[(size_t)row * N + col] = f2bf(v);
        else          ((float*)Cv)[(size_t)row * N + col] = v;
      }
    }
  }
}

// ---------------- fused h_pred + logits + softmax + out (d4/d5) -------------
// Block = 32 rows. Phase A: h_pred = tanh(PP [+ h_prev Us^T]) -> LDS.
// Phase B: logits = h_pred @ Wext^T + BE -> LDS (bf16).
// Phase C: log_softmax(cols<600) + sigmoid heads -> out.

template<int SZERO>
__global__ __launch_bounds__(256) void k_ls(
    const u16* __restrict__ PPm, const u16* __restrict__ Hprev,
    const u16* __restrict__ USw, const u16* __restrict__ WEXT,
    const float* __restrict__ BE, float* __restrict__ out,
    int pcs, int start_d, int s) {
  __shared__ __align__(16) u16 smem[27904];
  u16* sHp = smem;          // [32][264] h_pred
  u16* sAp = smem + 8448;   // [32][264] h_prev staging (phase A only)
  u16* sLg = smem + 8448;   // [32][608] logits bf16 (overlays sAp after A)
  const int g0 = blockIdx.x * 32;
  const int tid = threadIdx.x;
  const int wave = tid >> 6, lane = tid & 63;
  const int quad = lane >> 4, lr = lane & 15;

  if (SZERO) {
    for (int e = tid * 8; e < 8192; e += 2048) {
      int row = e >> 8, col = e & 255;
      bf16x8 v = *(const bf16x8*)&PPm[(size_t)(g0 + row) * 256 + col];
      bf16x8 ov;
#pragma unroll
      for (int j = 0; j < 8; ++j) ov[j] = (short)f2bf(tanhf(b2f((u16)v[j])));
      *(bf16x8*)&sHp[row * 264 + col] = ov;
    }
  } else {
    for (int e = tid * 8; e < 8192; e += 2048) {
      int row = e >> 8, col = e & 255;
      *(bf16x8*)&sAp[row * 264 + col] =
          *(const bf16x8*)&Hprev[(size_t)(g0 + row) * 256 + col];
    }
    __syncthreads();
    f32x4 acc[2][4] = {};
    for (int kk = 0; kk < 8; ++kk) {
      bf16x8 af[2], bv[4];
#pragma unroll
      for (int rt = 0; rt < 2; ++rt)
        af[rt] = *(const bf16x8*)&sAp[(rt * 16 + lr) * 264 + kk * 32 + quad * 8];
#pragma unroll
      for (int ct = 0; ct < 4; ++ct)
        bv[ct] = *(const bf16x8*)&USw[(size_t)(wave * 64 + ct * 16 + lr) * 256 + kk * 32 + quad * 8];
#pragma unroll
      for (int rt = 0; rt < 2; ++rt)
#pragma unroll
        for (int ct = 0; ct < 4; ++ct)
          acc[rt][ct] = __builtin_amdgcn_mfma_f32_16x16x32_bf16(
              af[rt], bv[ct], acc[rt][ct], 0, 0, 0);
    }
#pragma unroll
    for (int rt = 0; rt < 2; ++rt)
#pragma unroll
      for (int ct = 0; ct < 4; ++ct)
#pragma unroll
        for (int r = 0; r < 4; ++r) {
          int row = rt * 16 + quad * 4 + r;
          int col = wave * 64 + ct * 16 + lr;
          float v = acc[rt][ct][r] + b2f(PPm[(size_t)(g0 + row) * 256 + col]);
          sHp[row * 264 + col] = f2bf(tanhf(v));
        }
  }
  __syncthreads();  // sHp complete; sAp reads done (safe to overlay sLg)

  for (int tI = wave; tI < 10; tI += 4) {
    f32x4 acc[2][4] = {};
    for (int kk = 0; kk < 8; ++kk) {
      bf16x8 af[2], bv[4];
#pragma unroll
      for (int rt = 0; rt < 2; ++rt)
        af[rt] = *(const bf16x8*)&sHp[(rt * 16 + lr) * 264 + kk * 32 + quad * 8];
#pragma unroll
      for (int ct = 0; ct < 4; ++ct) {
        int c = tI * 64 + ct * 16 + lr; if (c > 601) c = 601;
        bv[ct] = *(const bf16x8*)&WEXT[(size_t)c * 256 + kk * 32 + quad * 8];
      }
#pragma unroll
      for (int rt = 0; rt < 2; ++rt)
#pragma unroll
        for (int ct = 0; ct < 4; ++ct)
          acc[rt][ct] = __builtin_amdgcn_mfma_f32_16x16x32_bf16(
              af[rt], bv[ct], acc[rt][ct], 0, 0, 0);
    }
#pragma unroll
    for (int rt = 0; rt < 2; ++rt)
#pragma unroll
      for (int ct = 0; ct < 4; ++ct)
#pragma unroll
        for (int r = 0; r < 4; ++r) {
          int col = tI * 64 + ct * 16 + lr;
          if (col < 602) {
            int row = rt * 16 + quad * 4 + r;
            sLg[row * 608 + col] = f2bf(acc[rt][ct][r] + BE[col]);
          }
        }
  }
  __syncthreads();

  int row = tid >> 3, sub = tid & 7;
  int g = g0 + row;
  int t = g >> pcs, j = g - (t << pcs);
  int idx = t * NPER + start_d + j * KARY + s;
  float* orow = out + (size_t)idx * 602;
  float m = -1e30f;
  for (int c = sub; c < 600; c += 8) m = fmaxf(m, b2f(sLg[row * 608 + c]));
  m = fmaxf(m, __shfl_xor(m, 1, 64));
  m = fmaxf(m, __shfl_xor(m, 2, 64));
  m = fmaxf(m, __shfl_xor(m, 4, 64));
  float sme = 0.f;
  for (int c = sub; c < 600; c += 8) sme += expf(b2f(sLg[row * 608 + c]) - m);
  sme += __shfl_xor(sme, 1, 64);
  sme += __shfl_xor(sme, 2, 64);
  sme += __shfl_xor(sme, 4, 64);
  float logZ = m + logf(sme);
  for (int c = sub; c < 600; c += 8) orow[c] = b2f(sLg[row * 608 + c]) - logZ;
  if (sub == 0) orow[600] = sigm(b2f(sLg[row * 608 + 600]));
  if (sub == 1) orow[601] = sigm(b2f(sLg[row * 608 + 601]));
}

// ---------------- fused sibling gates GEMM + LSTM elementwise (d4/d5, s>0) --
// Block = 16 rows; gates through LDS.

__global__ __launch_bounds__(256) void k_sib(
    const u16* __restrict__ Hprev, const u16* __restrict__ Cprev,
    const u16* __restrict__ WHHS, const u16* __restrict__ WIHST,
    const float* __restrict__ BS, const int* __restrict__ feat,
    u16* __restrict__ Hout, u16* __restrict__ Cout,
    int pcs, int start_d, int s) {
  __shared__ __align__(16) u16 sAp[16 * 264];   // 8448 B
  __shared__ __align__(16) u16 sG[16 * 1032];   // 33024 B
  const int g0 = blockIdx.x * 16;
  const int tid = threadIdx.x;
  const int wave = tid >> 6, lane = tid & 63;
  const int quad = lane >> 4, lr = lane & 15;

  for (int e = tid * 8; e < 4096; e += 2048) {
    int row = e >> 8, col = e & 255;
    *(bf16x8*)&sAp[row * 264 + col] =
        *(const bf16x8*)&Hprev[(size_t)(g0 + row) * 256 + col];
  }
  __syncthreads();
  f32x4 acc[16] = {};
  for (int kk = 0; kk < 8; ++kk) {
    bf16x8 af = *(const bf16x8*)&sAp[lr * 264 + kk * 32 + quad * 8];
#pragma unroll
    for (int ct = 0; ct < 16; ++ct) {
      bf16x8 bv = *(const bf16x8*)&WHHS[(size_t)(wave * 256 + ct * 16 + lr) * 256 + kk * 32 + quad * 8];
      acc[ct] = __builtin_amdgcn_mfma_f32_16x16x32_bf16(af, bv, acc[ct], 0, 0, 0);
    }
  }
#pragma unroll
  for (int ct = 0; ct < 16; ++ct)
#pragma unroll
    for (int r = 0; r < 4; ++r)
      sG[(quad * 4 + r) * 1032 + wave * 256 + ct * 16 + lr] = f2bf(acc[ct][r]);
  __syncthreads();

  int row = tid >> 4;
  int u0 = (tid & 15) * 16;
  int g = g0 + row;
  int t = g >> pcs, j = g - (t << pcs);
  int idx = t * NPER + start_d + j * KARY + s;
  int lab = feat[idx];
  const u16* wr = WIHST + (size_t)lab * 1024;
#pragma unroll 4
  for (int uu = 0; uu < 16; ++uu) {
    int u = u0 + uu;
    float gi = b2f(sG[row * 1032 + u])       + b2f(wr[u])       + BS[u];
    float gf = b2f(sG[row * 1032 + 256 + u]) + b2f(wr[256 + u]) + BS[256 + u];
    float gg = b2f(sG[row * 1032 + 512 + u]) + b2f(wr[512 + u]) + BS[512 + u];
    float go = b2f(sG[row * 1032 + 768 + u]) + b2f(wr[768 + u]) + BS[768 + u];
    float c = b2f(Cprev[(size_t)g * 256 + u]);
    float cn = sigm(gf) * c + sigm(gi) * tanhf(gg);
    float hn = sigm(go) * tanhf(cn);
    Hout[(size_t)g * 256 + u] = f2bf(hn);
    Cout[(size_t)g * 256 + u] = f2bf(cn);
  }
}

// ---------------- LSTM elementwise (d4 parent w/ hoisted gates; s==0 sib) ---

__global__ __launch_bounds__(256) void k_lstm(
    const u16* __restrict__ gate_gemm, const u16* __restrict__ wihT,
    const float* __restrict__ bias, const u16* __restrict__ c_in,
    const int* __restrict__ feat, u16* __restrict__ h_out, u16* __restrict__ c_out,
    int pcs, int LS, int start_d, int s, int strided) {
  int g = blockIdx.x, u = threadIdx.x;
  int t = g >> pcs, j = g - (t << pcs);
  int p = j * KARY + s;
  int idx = t * NPER + start_d + p;
  int lab = feat[idx];
  const u16* wr = wihT + (size_t)lab * 1024;
  float gi = b2f(wr[u])       + bias[u];
  float gf = b2f(wr[256 + u]) + bias[256 + u];
  float gg = b2f(wr[512 + u]) + bias[512 + u];
  float go = b2f(wr[768 + u]) + bias[768 + u];
  if (gate_gemm) {
    const u16* gr = gate_gemm + (size_t)g * 1024;
    gi += b2f(gr[u]); gf += b2f(gr[256 + u]);
    gg += b2f(gr[512 + u]); go += b2f(gr[768 + u]);
  }
  float c = c_in ? b2f(c_in[(size_t)g * 256 + u]) : 0.f;
  float cn = sigm(gf) * c + sigm(gi) * tanhf(gg);
  float hn = sigm(go) * tanhf(cn);
  int orow = strided ? (t * LS + p) : g;
  h_out[(size_t)orow * 256 + u] = f2bf(hn);
  c_out[(size_t)orow * 256 + u] = f2bf(cn);
}

// ---------------- fused whole-group kernel for small depths (d<=3) ----------
// ROWS rows per block; everything (h_pred, logits, softmax, both LSTMs) in one
// launch. Weights stream from L2; thread u owns output unit(s) u.

template<int SZERO, int ROWS>
__global__ __launch_bounds__(256) void k_small(
    const u16* __restrict__ Hpar, const u16* __restrict__ Cpar,
    const u16* __restrict__ Hprev, const u16* __restrict__ Cprev,
    const u16* __restrict__ UPw, const u16* __restrict__ USw,
    const u16* __restrict__ WEXT, const float* __restrict__ BE,
    const u16* __restrict__ WHHP, const u16* __restrict__ WIHPT,
    const float* __restrict__ BP, const u16* __restrict__ WHHS,
    const u16* __restrict__ WIHST, const float* __restrict__ BS,
    const int* __restrict__ feat, float* __restrict__ out,
    u16* __restrict__ HPn, u16* __restrict__ CPn,
    u16* __restrict__ HSn, u16* __restrict__ CSn,
    int pcs, int LS, int start_d, int s, int do_par, int do_sib) {
  __shared__ __align__(16) u16 sApar[4 * 264], sAprev[4 * 264], sHpred[4 * 264];
  __shared__ float sLg[4 * 604];
  __shared__ int sLab[4], sIdx[4], sOrow[4];
  const int tid = threadIdx.x;
  const int r0 = blockIdx.x * ROWS;
  if (tid < ROWS) {
    int r = r0 + tid;
    int t = r >> pcs, j = r - (t << pcs);
    int p = j * KARY + s;
    sLab[tid] = feat[t * NPER + start_d + p];
    sIdx[tid] = t * NPER + start_d + p;
    sOrow[tid] = t * LS + p;
  }
  for (int e = tid * 8; e < ROWS * 256; e += 2048) {
    int rr = e >> 8, c = e & 255;
    *(bf16x8*)&sApar[rr * 264 + c] = *(const bf16x8*)&Hpar[(size_t)(r0 + rr) * 256 + c];
    if (!SZERO)
      *(bf16x8*)&sAprev[rr * 264 + c] = *(const bf16x8*)&Hprev[(size_t)(r0 + rr) * 256 + c];
  }
  __syncthreads();
  // P1: h_pred
  {
    int u = tid;
    float acc[ROWS];
#pragma unroll
    for (int rr = 0; rr < ROWS; ++rr) acc[rr] = 0.f;
    const u16* w1 = UPw + (size_t)u * 256;
    const u16* w2 = USw + (size_t)u * 256;
    for (int k = 0; k < 256; k += 8) {
      bf16x8 wv = *(const bf16x8*)(w1 + k);
#pragma unroll
      for (int rr = 0; rr < ROWS; ++rr) {
        bf16x8 hv = *(const bf16x8*)&sApar[rr * 264 + k];
#pragma unroll
        for (int jj = 0; jj < 8; ++jj) acc[rr] += b2f((u16)wv[jj]) * b2f((u16)hv[jj]);
      }
      if (!SZERO) {
        bf16x8 wv2 = *(const bf16x8*)(w2 + k);
#pragma unroll
        for (int rr = 0; rr < ROWS; ++rr) {
          bf16x8 hv = *(const bf16x8*)&sAprev[rr * 264 + k];
#pragma unroll
          for (int jj = 0; jj < 8; ++jj) acc[rr] += b2f((u16)wv2[jj]) * b2f((u16)hv[jj]);
        }
      }
    }
#pragma unroll
    for (int rr = 0; rr < ROWS; ++rr) sHpred[rr * 264 + u] = f2bf(tanhf(acc[rr]));
  }
  __syncthreads();
  // P2: logits
  for (int u = tid; u < 602; u += 256) {
    float acc[ROWS];
#pragma unroll
    for (int rr = 0; rr < ROWS; ++rr) acc[rr] = 0.f;
    const u16* w1 = WEXT + (size_t)u * 256;
    for (int k = 0; k < 256; k += 8) {
      bf16x8 wv = *(const bf16x8*)(w1 + k);
#pragma unroll
      for (int rr = 0; rr < ROWS; ++rr) {
        bf16x8 hv = *(const bf16x8*)&sHpred[rr * 264 + k];
#pragma unroll
        for (int jj = 0; jj < 8; ++jj) acc[rr] += b2f((u16)wv[jj]) * b2f((u16)hv[jj]);
      }
    }
#pragma unroll
    for (int rr = 0; rr < ROWS; ++rr) sLg[rr * 604 + u] = acc[rr] + BE[u];
  }
  __syncthreads();
  // P3: softmax + out (wave w handles row w)
  if ((tid >> 6) < ROWS) {
    int rr = tid >> 6, lane = tid & 63;
    float m = -1e30f;
    for (int c = lane; c < 600; c += 64) m = fmaxf(m, sLg[rr * 604 + c]);
#pragma unroll
    for (int o = 32; o > 0; o >>= 1) m = fmaxf(m, __shfl_xor(m, o, 64));
    float sme = 0.f;
    for (int c = lane; c < 600; c += 64) sme += expf(sLg[rr * 604 + c] - m);
#pragma unroll
    for (int o = 32; o > 0; o >>= 1) sme += __shfl_xor(sme, o, 64);
    float logZ = m + logf(sme);
    float* orow = out + (size_t)sIdx[rr] * 602;
    for (int c = lane; c < 600; c += 64) orow[c] = sLg[rr * 604 + c] - logZ;
    if (lane == 0) orow[600] = sigm(sLg[rr * 604 + 600]);
    if (lane == 1) orow[601] = sigm(sLg[rr * 604 + 601]);
  }
  // P4: parent LSTM
  if (do_par) {
    int u = tid;
    float ag[4][ROWS];
#pragma unroll
    for (int g4 = 0; g4 < 4; ++g4)
#pragma unroll
      for (int rr = 0; rr < ROWS; ++rr) ag[g4][rr] = 0.f;
#pragma unroll
    for (int g4 = 0; g4 < 4; ++g4) {
      const u16* wrow = WHHP + (size_t)(g4 * 256 + u) * 256;
      for (int k = 0; k < 256; k += 8) {
        bf16x8 wv = *(const bf16x8*)(wrow + k);
#pragma unroll
        for (int rr = 0; rr < ROWS; ++rr) {
          bf16x8 hv = *(const bf16x8*)&sApar[rr * 264 + k];
#pragma unroll
          for (int jj = 0; jj < 8; ++jj) ag[g4][rr] += b2f((u16)wv[jj]) * b2f((u16)hv[jj]);
        }
      }
    }
#pragma unroll
    for (int rr = 0; rr < ROWS; ++rr) {
      const u16* er = WIHPT + (size_t)sLab[rr] * 1024;
      float gi = ag[0][rr] + b2f(er[u]) + BP[u];
      float gf = ag[1][rr] + b2f(er[256 + u]) + BP[256 + u];
      float gg = ag[2][rr] + b2f(er[512 + u]) + BP[512 + u];
      float go = ag[3][rr] + b2f(er[768 + u]) + BP[768 + u];
      float c = Cpar ? b2f(Cpar[(size_t)(r0 + rr) * 256 + u]) : 0.f;
      float cn = sigm(gf) * c + sigm(gi) * tanhf(gg);
      float hn = sigm(go) * tanhf(cn);
      HPn[(size_t)sOrow[rr] * 256 + u] = f2bf(hn);
      CPn[(size_t)sOrow[rr] * 256 + u] = f2bf(cn);
    }
  }
  // P5: sibling LSTM
  if (do_sib) {
    int u = tid;
    float ag[4][ROWS];
#pragma unroll
    for (int g4 = 0; g4 < 4; ++g4)
#pragma unroll
      for (int rr = 0; rr < ROWS; ++rr) ag[g4][rr] = 0.f;
    if (!SZERO) {
#pragma unroll
      for (int g4 = 0; g4 < 4; ++g4) {
        const u16* wrow = WHHS + (size_t)(g4 * 256 + u) * 256;
        for (int k = 0; k < 256; k += 8) {
          bf16x8 wv = *(const bf16x8*)(wrow + k);
#pragma unroll
          for (int rr = 0; rr < ROWS; ++rr) {
            bf16x8 hv = *(const bf16x8*)&sAprev[rr * 264 + k];
#pragma unroll
            for (int jj = 0; jj < 8; ++jj) ag[g4][rr] += b2f((u16)wv[jj]) * b2f((u16)hv[jj]);
          }
        }
      }
    }
#pragma unroll
    for (int rr = 0; rr < ROWS; ++rr) {
      const u16* er = WIHST + (size_t)sLab[rr] * 1024;
      float gi = ag[0][rr] + b2f(er[u]) + BS[u];
      float gf = ag[1][rr] + b2f(er[256 + u]) + BS[256 + u];
      float gg = ag[2][rr] + b2f(er[512 + u]) + BS[512 + u];
      float go = ag[3][rr] + b2f(er[768 + u]) + BS[768 + u];
      float c = SZERO ? 0.f : b2f(Cprev[(size_t)(r0 + rr) * 256 + u]);
      float cn = sigm(gf) * c + sigm(gi) * tanhf(gg);
      float hn = sigm(go) * tanhf(cn);
      HSn[(size_t)(r0 + rr) * 256 + u] = f2bf(hn);
      CSn[(size_t)(r0 + rr) * 256 + u] = f2bf(cn);
    }
  }
}

// ---------------- host ------------------------------------------------------

#define LMM(ACT, OBF, A, Bm, BIAS, CADD, C, M, N)                              \
  k_mm<ACT, OBF><<<dim3(((M) + 127) / 128, ((N) + 127) / 128), 256, 0,         \
                   stream>>>((const u16*)(A), (const u16*)(Bm), (BIAS),        \
                             (const u16*)(CADD), (void*)(C), (M), (N))

extern "C" void kernel_launch(void* const* d_in, const int* in_sizes, int n_in,
                              void* d_out, int out_size, void* d_ws, size_t ws_size,
                              hipStream_t stream) {
  const float* z    = (const float*)d_in[0];
  const int*   feat = (const int*)d_in[1];
  const float* Wihp = (const float*)d_in[2];
  const float* Whhp = (const float*)d_in[3];
  const float* bihp = (const float*)d_in[4];
  const float* bhhp = (const float*)d_in[5];
  const float* Wihs = (const float*)d_in[6];
  const float* Whhs = (const float*)d_in[7];
  const float* bihs = (const float*)d_in[8];
  const float* bhhs = (const float*)d_in[9];
  const float* Upar = (const float*)d_in[10];
  const float* Usib = (const float*)d_in[11];
  const float* Wlab = (const float*)d_in[12];
  const float* blab = (const float*)d_in[13];
  const float* Wd   = (const float*)d_in[14];
  const float* bd   = (const float*)d_in[15];
  const float* Ww   = (const float*)d_in[16];
  const float* bw   = (const float*)d_in[17];
  float* out = (float*)d_out;

  char* w = (char*)d_ws;
  auto alloc = [&](size_t bytes) {
    char* p = w; w += (bytes + 255) & ~(size_t)255; return p;
  };
  u16*   UP    = (u16*)alloc(65536 * 2);
  u16*   US    = (u16*)alloc(65536 * 2);
  u16*   WEXT  = (u16*)alloc(602 * 256 * 2);
  float* BE    = (float*)alloc(602 * 4);
  u16*   WHHP  = (u16*)alloc(1024 * 256 * 2);
  u16*   WHHS  = (u16*)alloc(1024 * 256 * 2);
  u16*   WIHPT = (u16*)alloc(600 * 1024 * 2);
  u16*   WIHST = (u16*)alloc(600 * 1024 * 2);
  float* BP    = (float*)alloc(1024 * 4);
  float* BS    = (float*)alloc(1024 * 4);
  u16*   ZBF   = (u16*)alloc(64 * 256 * 2);
  const size_t SB = (size_t)16384 * 256 * 2;
  u16* HP[2] = {(u16*)alloc(SB), (u16*)alloc(SB)};
  u16* CP[2] = {(u16*)alloc(SB), (u16*)alloc(SB)};
  u16* HS[2] = {(u16*)alloc(SB), (u16*)alloc(SB)};
  u16* CS[2] = {(u16*)alloc(SB), (u16*)alloc(SB)};
  u16*   PP     = (u16*)alloc(SB);
  u16*   GATESP = (u16*)alloc((size_t)4096 * 1024 * 2);

  k_pack<<<4096, 256, 0, stream>>>(z, Wihp, Whhp, bihp, bhhp, Wihs, Whhs, bihs,
                                   bhhs, Upar, Usib, Wlab, blab, Wd, bd, Ww, bw,
                                   UP, US, WHHP, WHHS, ZBF, WIHPT, WIHST, WEXT,
                                   BE, BP, BS);

  auto launch_small = [&](int SZ, int ROWS, int G, const u16* Hp_, const u16* Cp_,
                          const u16* Hs_, const u16* Cs_, int pcs, int LS, int st,
                          int s, int do_par, int do_sib, u16* HPn, u16* CPn,
                          u16* HSn, u16* CSn) {
    dim3 gr(G / ROWS);
#define SM_ARGS Hp_, Cp_, Hs_, Cs_, UP, US, WEXT, BE, WHHP, WIHPT, BP, WHHS,   \
                WIHST, BS, feat, out, HPn, CPn, HSn, CSn, pcs, LS, st, s,      \
                do_par, do_sib
    if (SZ) {
      if (ROWS == 1)      k_small<1, 1><<<gr, 256, 0, stream>>>(SM_ARGS);
      else if (ROWS == 2) k_small<1, 2><<<gr, 256, 0, stream>>>(SM_ARGS);
      else                k_small<1, 4><<<gr, 256, 0, stream>>>(SM_ARGS);
    } else {
      if (ROWS == 1)      k_small<0, 1><<<gr, 256, 0, stream>>>(SM_ARGS);
      else if (ROWS == 2) k_small<0, 2><<<gr, 256, 0, stream>>>(SM_ARGS);
      else                k_small<0, 4><<<gr, 256, 0, stream>>>(SM_ARGS);
    }
#undef SM_ARGS
  };

  const int starts[6] = {0, 1, 5, 21, 85, 341};

  // d = 0 (roots): h_par = z, c_par = 0, no sibling output needed
  launch_small(1, 1, 64, ZBF, nullptr, nullptr, nullptr, 0, 1, 0, 0, 1, 0,
               HP[0], CP[0], nullptr, nullptr);
  int hp = 0;

  // d = 1..3: fused small-group kernels
  const int rows_d[4] = {0, 1, 2, 4};
  for (int d = 1; d <= 3; ++d) {
    int G = 64 << (2 * (d - 1));
    int pcs = 2 * (d - 1), LS = 1 << (2 * d), st = starts[d];
    int sp = -1;
    for (int s = 0; s < 4; ++s) {
      int do_sib = (s < 3);
      int dst = (sp < 0) ? 0 : 1 - sp;
      launch_small(s == 0, rows_d[d], G, HP[hp], CP[hp],
                   s ? HS[sp] : nullptr, s ? CS[sp] : nullptr,
                   pcs, LS, st, s, 1, do_sib,
                   HP[1 - hp], CP[1 - hp],
                   do_sib ? HS[dst] : nullptr, do_sib ? CS[dst] : nullptr);
      if (do_sib) sp = dst;
    }
    hp = 1 - hp;
  }

  // d = 4, 5: MFMA path
  for (int d = 4; d <= 5; ++d) {
    int G = 64 << (2 * (d - 1));
    int pcs = 2 * (d - 1), LS = 1 << (2 * d), st = starts[d];
    LMM(0, 1, HP[hp], UP, nullptr, nullptr, PP, G, 256);
    if (d == 4) LMM(0, 1, HP[hp], WHHP, nullptr, nullptr, GATESP, G, 1024);
    int sp = -1;
    for (int s = 0; s < 4; ++s) {
      if (s == 0)
        k_ls<1><<<G / 32, 256, 0, stream>>>(PP, nullptr, US, WEXT, BE, out, pcs, st, s);
      else
        k_ls<0><<<G / 32, 256, 0, stream>>>(PP, HS[sp], US, WEXT, BE, out, pcs, st, s);
      if (d == 4)
        k_lstm<<<G, 256, 0, stream>>>(GATESP, WIHPT, BP, CP[hp], feat,
                                      HP[1 - hp], CP[1 - hp], pcs, LS, st, s, 1);
      if (s < 3) {
        int dst = (sp < 0) ? 0 : 1 - sp;
        if (s == 0)
          k_lstm<<<G, 256, 0, stream>>>(nullptr, WIHST, BS, nullptr, feat,
                                        HS[dst], CS[dst], pcs, LS, st, s, 0);
        else
          k_sib<<<G / 16, 256, 0, stream>>>(HS[sp], CS[sp], WHHS, WIHST, BS, feat,
                                            HS[dst], CS[dst], pcs, st, s);
        sp = dst;
      }
    }
    if (d == 4) hp = 1 - hp;
  }
  (void)in_sizes; (void)n_in; (void)out_size; (void)ws_size;
}